// Round 6
// baseline (259.872 us; speedup 1.0000x reference)
//
#include <hip/hip_runtime.h>

#define T_SEQ 2048
#define DIM   768
#define NH    12
#define HD    64

typedef __attribute__((ext_vector_type(8))) short short8;
typedef __attribute__((ext_vector_type(4))) float floatx4;
typedef __attribute__((ext_vector_type(4))) unsigned short ushort4v;

#define MFMA16(a,b,c) __builtin_amdgcn_mfma_f32_16x16x32_bf16((a),(b),(c),0,0,0)

static __device__ __forceinline__ unsigned short f2bf(float f){
  union { float f; unsigned u; } v; v.f = f;
  unsigned r = v.u + 0x7fffu + ((v.u >> 16) & 1u);
  return (unsigned short)(r >> 16);
}

// async global->LDS, 16B per lane; lds dest = wave-uniform base + lane*16
static __device__ __forceinline__ void async16(const unsigned short* g,
                                               unsigned short* l){
  __builtin_amdgcn_global_load_lds(
      (__attribute__((address_space(1))) void*)(unsigned long long)(const void*)g,
      (__attribute__((address_space(3))) void*)l,
      16, 0, 0);
}

// ---------------- fp32 -> bf16 conversion of x, Wq|Wk|Wv, Wp ----------------
__global__ void convert_kernel(const float* __restrict__ x,
                               const float* __restrict__ wq,
                               const float* __restrict__ wk,
                               const float* __restrict__ wv,
                               const float* __restrict__ wp,
                               unsigned short* __restrict__ xb,
                               unsigned short* __restrict__ wqkvb,
                               unsigned short* __restrict__ wpb){
  const int stride = gridDim.x * blockDim.x;
  const int i0 = blockIdx.x * blockDim.x + threadIdx.x;
  const int XN = T_SEQ * DIM;
  const int WN = DIM * DIM;
  for (int i = i0; i < XN; i += stride) xb[i] = f2bf(x[i]);
  for (int i = i0; i < WN; i += stride) {
    wqkvb[i]        = f2bf(wq[i]);
    wqkvb[WN + i]   = f2bf(wk[i]);
    wqkvb[2*WN + i] = f2bf(wv[i]);
    wpb[i]          = f2bf(wp[i]);
  }
}

// ---------------- QKV projection: 128x128 LDS-staged MFMA GEMM --------------
// grid (16, 18); cb/6 = {q,k,v}, (cb%6)*128 = col base within matrix.
// block = 4 waves in 2x2; wave tile 64x64 (4x4 MFMA acc).
__global__ __launch_bounds__(256) void qkv_kernel(
    const unsigned short* __restrict__ xb,
    const unsigned short* __restrict__ wqkvb,
    const float* __restrict__ vi,
    const float* __restrict__ lambp,
    unsigned short* __restrict__ qb,   // [NH][T][HD]
    unsigned short* __restrict__ kb,   // [NH][T][HD]
    unsigned short* __restrict__ vT){  // [NH][HD][T]
  __shared__ unsigned short Al[128*32];
  __shared__ unsigned short Bl[128*32];
  const int tid = threadIdx.x;
  const int w  = tid >> 6, l = tid & 63;
  const int lr = l & 15, lq = l >> 4;
  const int wr = w >> 1, wc = w & 1;
  const int rb = blockIdx.x, cb = blockIdx.y;
  const int mat  = cb / 6;
  const int col0 = (cb % 6) * 128;
  const int row0 = rb * 128;

  const int srow = l >> 2, scol = (l & 3) * 8;   // staging: 16 rows x 32 cols / wave-call
  const unsigned short* Ag = xb + (size_t)(row0 + srow)*DIM + scol;
  const unsigned short* Bg = wqkvb + (size_t)mat*DIM*DIM
                           + (size_t)(col0 + srow)*DIM + scol;

  floatx4 acc[4][4];
  #pragma unroll
  for (int i=0;i<4;i++)
    #pragma unroll
    for (int j=0;j<4;j++) acc[i][j] = (floatx4){0.f,0.f,0.f,0.f};

  for (int k0 = 0; k0 < DIM; k0 += 32){
    #pragma unroll
    for (int j=0;j<2;j++){
      const int rr = (w*2 + j)*16;
      async16(Ag + (size_t)rr*DIM + k0, &Al[rr*32]);
      async16(Bg + (size_t)rr*DIM + k0, &Bl[rr*32]);
    }
    __syncthreads();
    short8 af[4], bf[4];
    #pragma unroll
    for (int rt=0;rt<4;rt++) af[rt] = *(const short8*)&Al[(wr*64+rt*16+lr)*32 + lq*8];
    #pragma unroll
    for (int ct=0;ct<4;ct++) bf[ct] = *(const short8*)&Bl[(wc*64+ct*16+lr)*32 + lq*8];
    #pragma unroll
    for (int rt=0;rt<4;rt++)
      #pragma unroll
      for (int ct=0;ct<4;ct++)
        acc[rt][ct] = MFMA16(af[rt], bf[ct], acc[rt][ct]);
    __syncthreads();
  }

  const int head = (cb % 6)*2 + wc;
  if (mat == 2){
    const float lamb = *lambp;
    #pragma unroll
    for (int rt=0;rt<4;rt++){
      const int tb = row0 + wr*64 + rt*16 + lq*4;
      #pragma unroll
      for (int ct=0;ct<4;ct++){
        const int d = ct*16 + lr;
        ushort4v pk;
        #pragma unroll
        for (int r=0;r<4;r++){
          float vv = (1.0f - lamb)*acc[rt][ct][r]
                   + lamb * vi[(size_t)(tb + r)*DIM + head*HD + d];
          pk[r] = f2bf(vv);
        }
        *(ushort4v*)(vT + (size_t)(head*HD + d)*T_SEQ + tb) = pk;
      }
    }
  } else {
    unsigned short* dst = (mat==0 ? qb : kb) + (size_t)head*T_SEQ*HD;
    #pragma unroll
    for (int rt=0;rt<4;rt++){
      float ss[4];
      #pragma unroll
      for (int r=0;r<4;r++)
        ss[r] = acc[rt][0][r]*acc[rt][0][r] + acc[rt][1][r]*acc[rt][1][r]
              + acc[rt][2][r]*acc[rt][2][r] + acc[rt][3][r]*acc[rt][3][r];
      #pragma unroll
      for (int mm=1; mm<16; mm<<=1){
        #pragma unroll
        for (int r=0;r<4;r++) ss[r] += __shfl_xor(ss[r], mm);
      }
      float scl[4];
      #pragma unroll
      for (int r=0;r<4;r++)
        scl[r] = rsqrtf(ss[r]*(1.0f/64.0f) + 1.1920929e-7f);

      #pragma unroll
      for (int ct=0;ct<2;ct++){
        const int i = ct*16 + lr;               // rope pair index 0..31
        const float inv = __expf(-(float)i * (9.210340371976184f/32.0f));
        #pragma unroll
        for (int r=0;r<4;r++){
          const int t = row0 + wr*64 + rt*16 + lq*4 + r;
          const float f = (float)t * inv;
          const float c = cosf(f), s = sinf(f);
          const float x1 = acc[rt][ct][r]*scl[r], x2 = acc[rt][ct+2][r]*scl[r];
          dst[(size_t)t*HD + i]      = f2bf(x1*c + x2*s);
          dst[(size_t)t*HD + i + 32] = f2bf(x2*c - x1*s);
        }
      }
    }
  }
}

// ---------------- causal flash attention (MFMA, fixed-max softmax) ----------
__global__ __launch_bounds__(256) void attn_kernel(
    const unsigned short* __restrict__ qb,
    const unsigned short* __restrict__ kb,
    const unsigned short* __restrict__ vT,
    unsigned short* __restrict__ yb){   // [T][DIM] token-major
  __shared__ unsigned short plds[2][4][16*40];
  __shared__ float Oshf[4][64][16];
  __shared__ float lsh[4][16];
  const int w  = threadIdx.x >> 6;
  const int l  = threadIdx.x & 63;
  const int lr = l & 15, lq = l >> 4;
  const int head = blockIdx.y;

  const unsigned short* Q = qb + (size_t)head*T_SEQ*HD;
  const unsigned short* K = kb + (size_t)head*T_SEQ*HD;
  const unsigned short* V = vT + (size_t)head*HD*T_SEQ;

  #pragma unroll
  for (int ph = 0; ph < 2; ph++){
    const int qt = ph ? (127 - (int)blockIdx.x) : (int)blockIdx.x;
    const int q0 = qt*16;

    const short8 qf0 = *(const short8*)(Q + (size_t)(q0+lr)*HD + lq*8);
    const short8 qf1 = *(const short8*)(Q + (size_t)(q0+lr)*HD + 32 + lq*8);

    floatx4 O[4];
    #pragma unroll
    for (int nt=0; nt<4; nt++) O[nt] = (floatx4){0.f,0.f,0.f,0.f};
    float lsum[4] = {0.f,0.f,0.f,0.f};

    const int ntile = (q0 + 15)/32 + 1;
    int kt = w;
    short8 kf0, kf1, kf2, kf3;
    if (kt < ntile){
      const unsigned short* kp = K + (size_t)(kt*32 + lr)*HD + lq*8;
      kf0 = *(const short8*)kp;            kf1 = *(const short8*)(kp + 32);
      kf2 = *(const short8*)(kp + 16*HD);  kf3 = *(const short8*)(kp + 16*HD + 32);
    }
    int dbuf = 0;
    for (; kt < ntile; kt += 4, dbuf ^= 1){
      const int kbase = kt*32;
      short8 vf[4];
      #pragma unroll
      for (int nt=0; nt<4; nt++)
        vf[nt] = *(const short8*)(V + (size_t)(nt*16 + lr)*T_SEQ + kbase + lq*8);

      floatx4 S0 = (floatx4){0.f,0.f,0.f,0.f};
      floatx4 S1 = (floatx4){0.f,0.f,0.f,0.f};
      S0 = MFMA16(qf0, kf0, S0);
      S0 = MFMA16(qf1, kf1, S0);
      S1 = MFMA16(qf0, kf2, S1);
      S1 = MFMA16(qf1, kf3, S1);

      const int ktn = kt + 4;
      if (ktn < ntile){
        const unsigned short* kp = K + (size_t)(ktn*32 + lr)*HD + lq*8;
        kf0 = *(const short8*)kp;            kf1 = *(const short8*)(kp + 32);
        kf2 = *(const short8*)(kp + 16*HD);  kf3 = *(const short8*)(kp + 16*HD + 32);
      }

      float p0[4], p1[4];
      const int qr = q0 + lq*4;
      #pragma unroll
      for (int r=0; r<4; r++){
        float e0 = __builtin_amdgcn_exp2f(S0[r]*0.18033688011112043f - 11.541560327111707f);
        float e1 = __builtin_amdgcn_exp2f(S1[r]*0.18033688011112043f - 11.541560327111707f);
        p0[r] = (kbase + lr      > qr + r) ? 0.f : e0;
        p1[r] = (kbase + 16 + lr > qr + r) ? 0.f : e1;
        lsum[r] += p0[r] + p1[r];
      }

      unsigned short* pl = &plds[dbuf][w][0];
      #pragma unroll
      for (int r=0; r<4; r++){
        const int row = lq*4 + r;
        pl[row*40 + lr]      = f2bf(p0[r]);
        pl[row*40 + 16 + lr] = f2bf(p1[r]);
      }
      __asm__ volatile("s_waitcnt lgkmcnt(0)" ::: "memory");
      const short8 pf = *(const short8*)(pl + lr*40 + lq*8);

      #pragma unroll
      for (int nt=0; nt<4; nt++) O[nt] = MFMA16(pf, vf[nt], O[nt]);
    }

    #pragma unroll
    for (int mm=1; mm<16; mm<<=1){
      #pragma unroll
      for (int r=0; r<4; r++) lsum[r] += __shfl_xor(lsum[r], mm);
    }

    if (lr == 0){
      #pragma unroll
      for (int r=0; r<4; r++) lsh[w][lq*4+r] = lsum[r];
    }
    #pragma unroll
    for (int nt=0; nt<4; nt++) *(floatx4*)&Oshf[w][l][nt*4] = O[nt];
    __syncthreads();

    if (w == 0){
      float L[4] = {0.f,0.f,0.f,0.f};
      float Of[4][4];
      #pragma unroll
      for (int nt=0; nt<4; nt++)
        #pragma unroll
        for (int r=0; r<4; r++) Of[nt][r] = 0.f;
      #pragma unroll
      for (int ww=0; ww<4; ww++){
        #pragma unroll
        for (int r=0; r<4; r++) L[r] += lsh[ww][lq*4+r];
        #pragma unroll
        for (int nt=0; nt<4; nt++){
          floatx4 t = *(const floatx4*)&Oshf[ww][l][nt*4];
          #pragma unroll
          for (int r=0; r<4; r++) Of[nt][r] += t[r];
        }
      }
      #pragma unroll
      for (int nt=0; nt<4; nt++){
        #pragma unroll
        for (int r=0; r<4; r++){
          yb[(size_t)(q0 + lq*4 + r)*DIM + head*HD + nt*16 + lr]
              = f2bf(Of[nt][r] / L[r]);
        }
      }
    }
    __syncthreads();
  }
}

// ---------------- output projection: 128x128 LDS-staged GEMM, fp32 out ------
// grid (16, 6)
__global__ __launch_bounds__(256) void proj_kernel(
    const unsigned short* __restrict__ yb,
    const unsigned short* __restrict__ wpb,
    float* __restrict__ out){
  __shared__ unsigned short Al[128*32];
  __shared__ unsigned short Bl[128*32];
  const int tid = threadIdx.x;
  const int w  = tid >> 6, l = tid & 63;
  const int lr = l & 15, lq = l >> 4;
  const int wr = w >> 1, wc = w & 1;
  const int rb = blockIdx.x, cb = blockIdx.y;
  const int col0 = cb * 128;
  const int row0 = rb * 128;

  const int srow = l >> 2, scol = (l & 3) * 8;
  const unsigned short* Ag = yb + (size_t)(row0 + srow)*DIM + scol;
  const unsigned short* Bg = wpb + (size_t)(col0 + srow)*DIM + scol;

  floatx4 acc[4][4];
  #pragma unroll
  for (int i=0;i<4;i++)
    #pragma unroll
    for (int j=0;j<4;j++) acc[i][j] = (floatx4){0.f,0.f,0.f,0.f};

  for (int k0 = 0; k0 < DIM; k0 += 32){
    #pragma unroll
    for (int j=0;j<2;j++){
      const int rr = (w*2 + j)*16;
      async16(Ag + (size_t)rr*DIM + k0, &Al[rr*32]);
      async16(Bg + (size_t)rr*DIM + k0, &Bl[rr*32]);
    }
    __syncthreads();
    short8 af[4], bf[4];
    #pragma unroll
    for (int rt=0;rt<4;rt++) af[rt] = *(const short8*)&Al[(wr*64+rt*16+lr)*32 + lq*8];
    #pragma unroll
    for (int ct=0;ct<4;ct++) bf[ct] = *(const short8*)&Bl[(wc*64+ct*16+lr)*32 + lq*8];
    #pragma unroll
    for (int rt=0;rt<4;rt++)
      #pragma unroll
      for (int ct=0;ct<4;ct++)
        acc[rt][ct] = MFMA16(af[rt], bf[ct], acc[rt][ct]);
    __syncthreads();
  }

  #pragma unroll
  for (int rt=0;rt<4;rt++){
    #pragma unroll
    for (int ct=0;ct<4;ct++){
      const int col = col0 + wc*64 + ct*16 + lr;
      #pragma unroll
      for (int r=0;r<4;r++){
        const int row = row0 + wr*64 + rt*16 + lq*4 + r;
        out[(size_t)row*DIM + col] = acc[rt][ct][r];
      }
    }
  }
}

extern "C" void kernel_launch(void* const* d_in, const int* in_sizes, int n_in,
                              void* d_out, int out_size, void* d_ws, size_t ws_size,
                              hipStream_t stream){
  const float* x   = (const float*)d_in[0];
  const float* vi  = (const float*)d_in[1];
  const float* Wq  = (const float*)d_in[2];
  const float* Wk  = (const float*)d_in[3];
  const float* Wv  = (const float*)d_in[4];
  const float* Wp  = (const float*)d_in[5];
  const float* lamb= (const float*)d_in[6];

  const size_t XN = (size_t)T_SEQ*DIM;   // 1572864
  const size_t WN = (size_t)DIM*DIM;     // 589824
  char* ws = (char*)d_ws;
  unsigned short* xb    = (unsigned short*)ws; ws += XN*2;
  unsigned short* wqkvb = (unsigned short*)ws; ws += 3*WN*2;
  unsigned short* wpb   = (unsigned short*)ws; ws += WN*2;
  unsigned short* qb    = (unsigned short*)ws; ws += XN*2;
  unsigned short* kb    = (unsigned short*)ws; ws += XN*2;
  unsigned short* vT    = (unsigned short*)ws; ws += XN*2;
  unsigned short* yb    = xb;  // alias: xb dead after qkv_kernel

  convert_kernel<<<1024, 256, 0, stream>>>(x, Wq, Wk, Wv, Wp, xb, wqkvb, wpb);
  qkv_kernel<<<dim3(16,18), 256, 0, stream>>>(xb, wqkvb, vi, lamb, qb, kb, vT);
  attn_kernel<<<dim3(64,12), 256, 0, stream>>>(qb, kb, vT, yb);
  proj_kernel<<<dim3(16,6), 256, 0, stream>>>(yb, wpb, (float*)d_out);
}

// Round 7
// 227.081 us; speedup vs baseline: 1.1444x; 1.1444x over previous
//
#include <hip/hip_runtime.h>

#define T_SEQ 2048
#define DIM   768
#define NH    12
#define HD    64

typedef __attribute__((ext_vector_type(8))) short short8;
typedef __attribute__((ext_vector_type(4))) float floatx4;
typedef __attribute__((ext_vector_type(4))) unsigned short ushort4v;

#define MFMA16(a,b,c) __builtin_amdgcn_mfma_f32_16x16x32_bf16((a),(b),(c),0,0,0)

static __device__ __forceinline__ unsigned short f2bf(float f){
  union { float f; unsigned u; } v; v.f = f;
  unsigned r = v.u + 0x7fffu + ((v.u >> 16) & 1u);
  return (unsigned short)(r >> 16);
}

// ---------------- fp32 -> bf16 conversion of x, Wq|Wk|Wv, Wp ----------------
__global__ void convert_kernel(const float* __restrict__ x,
                               const float* __restrict__ wq,
                               const float* __restrict__ wk,
                               const float* __restrict__ wv,
                               const float* __restrict__ wp,
                               unsigned short* __restrict__ xb,
                               unsigned short* __restrict__ wqkvb,
                               unsigned short* __restrict__ wpb){
  const int stride = gridDim.x * blockDim.x;
  const int i0 = blockIdx.x * blockDim.x + threadIdx.x;
  const int XN = T_SEQ * DIM;
  const int WN = DIM * DIM;
  for (int i = i0; i < XN; i += stride) xb[i] = f2bf(x[i]);
  for (int i = i0; i < WN; i += stride) {
    wqkvb[i]        = f2bf(wq[i]);
    wqkvb[WN + i]   = f2bf(wk[i]);
    wqkvb[2*WN + i] = f2bf(wv[i]);
    wpb[i]          = f2bf(wp[i]);
  }
}

// ---------------- QKV projection + lerp + rmsnorm + rope --------------------
// grid (32 row-blocks, 36 col-blocks): cb/12 = {q,k,v}, cb%12 = head.
// Direct global fragment loads with explicit next-step register prefetch
// (keeps ~5 loads in flight per wave; VGPR36-era version serialized them).
__global__ __launch_bounds__(256) void qkv_kernel(
    const unsigned short* __restrict__ xb,
    const unsigned short* __restrict__ wqkvb,
    const float* __restrict__ vi,
    const float* __restrict__ lambp,
    unsigned short* __restrict__ qb,   // [NH][T][HD]
    unsigned short* __restrict__ kb,   // [NH][T][HD]
    unsigned short* __restrict__ vT){  // [NH][HD][T]
  const int w  = threadIdx.x >> 6;
  const int l  = threadIdx.x & 63;
  const int lr = l & 15, lq = l >> 4;
  const int rb = blockIdx.x, cb = blockIdx.y;
  const int mat = cb / NH, head = cb % NH;
  const int row0 = rb*64 + w*16;

  floatx4 acc[4];
  #pragma unroll
  for (int nt=0; nt<4; nt++) acc[nt] = (floatx4){0.f,0.f,0.f,0.f};

  const unsigned short* arow = xb + (size_t)(row0 + lr)*DIM + lq*8;
  const unsigned short* b0   = wqkvb + (size_t)mat*DIM*DIM
                             + (size_t)(head*HD + lr)*DIM + lq*8;

  short8 a = *(const short8*)(arow);
  short8 b[4];
  #pragma unroll
  for (int nt=0; nt<4; nt++) b[nt] = *(const short8*)(b0 + (size_t)nt*16*DIM);

  for (int k0 = 0; k0 < DIM; k0 += 32){
    const int kn = (k0 + 32 < DIM) ? k0 + 32 : 0;   // wrap tail: loads stay unconditional
    short8 an = *(const short8*)(arow + kn);
    short8 bn[4];
    #pragma unroll
    for (int nt=0; nt<4; nt++) bn[nt] = *(const short8*)(b0 + (size_t)nt*16*DIM + kn);
    #pragma unroll
    for (int nt=0; nt<4; nt++) acc[nt] = MFMA16(a, b[nt], acc[nt]);
    a = an;
    #pragma unroll
    for (int nt=0; nt<4; nt++) b[nt] = bn[nt];
  }

  if (mat == 2){
    const float lamb = *lambp;
    const int tb = row0 + lq*4;
    #pragma unroll
    for (int nt=0; nt<4; nt++){
      const int d = nt*16 + lr;
      ushort4v pk;
      #pragma unroll
      for (int r=0; r<4; r++){
        float vv = (1.0f - lamb)*acc[nt][r]
                 + lamb * vi[(size_t)(tb + r)*DIM + head*HD + d];
        pk[r] = f2bf(vv);
      }
      *(ushort4v*)(vT + (size_t)(head*HD + d)*T_SEQ + tb) = pk;
    }
  } else {
    float ss[4];
    #pragma unroll
    for (int r=0; r<4; r++)
      ss[r] = acc[0][r]*acc[0][r] + acc[1][r]*acc[1][r]
            + acc[2][r]*acc[2][r] + acc[3][r]*acc[3][r];
    #pragma unroll
    for (int mm=1; mm<16; mm<<=1){
      #pragma unroll
      for (int r=0; r<4; r++) ss[r] += __shfl_xor(ss[r], mm);
    }
    float scl[4];
    #pragma unroll
    for (int r=0; r<4; r++)
      scl[r] = rsqrtf(ss[r]*(1.0f/64.0f) + 1.1920929e-7f);

    unsigned short* dst = (mat==0 ? qb : kb) + (size_t)head*T_SEQ*HD;
    #pragma unroll
    for (int nt=0; nt<2; nt++){
      const int i = nt*16 + lr;                 // rope pair index, 0..31
      const float inv = __expf(-(float)i * (9.210340371976184f/32.0f));
      #pragma unroll
      for (int r=0; r<4; r++){
        const int t = row0 + lq*4 + r;
        const float f = (float)t * inv;
        const float c = cosf(f), s = sinf(f);
        const float x1 = acc[nt][r]*scl[r], x2 = acc[nt+2][r]*scl[r];
        dst[(size_t)t*HD + i]      = f2bf(x1*c + x2*s);
        dst[(size_t)t*HD + i + 32] = f2bf(x2*c - x1*s);
      }
    }
  }
}

// ---------------- causal flash attention (MFMA, fixed-max softmax) ----------
// Scores bounded: rmsnorm rows have norm 8 => s = q.k/8 in [-8,8]; fixed max.
// grid (64, 12): block b handles q-tiles b and 127-b (balanced).
__global__ __launch_bounds__(256) void attn_kernel(
    const unsigned short* __restrict__ qb,
    const unsigned short* __restrict__ kb,
    const unsigned short* __restrict__ vT,
    unsigned short* __restrict__ yb){   // [T][DIM] token-major
  __shared__ unsigned short plds[2][4][16*40];
  __shared__ float Oshf[4][64][16];
  __shared__ float lsh[4][16];
  const int w  = threadIdx.x >> 6;
  const int l  = threadIdx.x & 63;
  const int lr = l & 15, lq = l >> 4;
  const int head = blockIdx.y;

  const unsigned short* Q = qb + (size_t)head*T_SEQ*HD;
  const unsigned short* K = kb + (size_t)head*T_SEQ*HD;
  const unsigned short* V = vT + (size_t)head*HD*T_SEQ;

  #pragma unroll
  for (int ph = 0; ph < 2; ph++){
    const int qt = ph ? (127 - (int)blockIdx.x) : (int)blockIdx.x;
    const int q0 = qt*16;

    const short8 qf0 = *(const short8*)(Q + (size_t)(q0+lr)*HD + lq*8);
    const short8 qf1 = *(const short8*)(Q + (size_t)(q0+lr)*HD + 32 + lq*8);

    floatx4 O[4];
    #pragma unroll
    for (int nt=0; nt<4; nt++) O[nt] = (floatx4){0.f,0.f,0.f,0.f};
    float lsum[4] = {0.f,0.f,0.f,0.f};

    const int ntile = (q0 + 15)/32 + 1;
    int kt = w;
    short8 kf0, kf1, kf2, kf3;
    if (kt < ntile){
      const unsigned short* kp = K + (size_t)(kt*32 + lr)*HD + lq*8;
      kf0 = *(const short8*)kp;            kf1 = *(const short8*)(kp + 32);
      kf2 = *(const short8*)(kp + 16*HD);  kf3 = *(const short8*)(kp + 16*HD + 32);
    }
    int dbuf = 0;
    for (; kt < ntile; kt += 4, dbuf ^= 1){
      const int kbase = kt*32;
      short8 vf[4];
      #pragma unroll
      for (int nt=0; nt<4; nt++)
        vf[nt] = *(const short8*)(V + (size_t)(nt*16 + lr)*T_SEQ + kbase + lq*8);

      floatx4 S0 = (floatx4){0.f,0.f,0.f,0.f};
      floatx4 S1 = (floatx4){0.f,0.f,0.f,0.f};
      S0 = MFMA16(qf0, kf0, S0);
      S0 = MFMA16(qf1, kf1, S0);
      S1 = MFMA16(qf0, kf2, S1);
      S1 = MFMA16(qf1, kf3, S1);

      const int ktn = kt + 4;
      if (ktn < ntile){
        const unsigned short* kp = K + (size_t)(ktn*32 + lr)*HD + lq*8;
        kf0 = *(const short8*)kp;            kf1 = *(const short8*)(kp + 32);
        kf2 = *(const short8*)(kp + 16*HD);  kf3 = *(const short8*)(kp + 16*HD + 32);
      }

      float p0[4], p1[4];
      const int qr = q0 + lq*4;
      #pragma unroll
      for (int r=0; r<4; r++){
        float e0 = __builtin_amdgcn_exp2f(S0[r]*0.18033688011112043f - 11.541560327111707f);
        float e1 = __builtin_amdgcn_exp2f(S1[r]*0.18033688011112043f - 11.541560327111707f);
        p0[r] = (kbase + lr      > qr + r) ? 0.f : e0;
        p1[r] = (kbase + 16 + lr > qr + r) ? 0.f : e1;
        lsum[r] += p0[r] + p1[r];
      }

      unsigned short* pl = &plds[dbuf][w][0];
      #pragma unroll
      for (int r=0; r<4; r++){
        const int row = lq*4 + r;
        pl[row*40 + lr]      = f2bf(p0[r]);
        pl[row*40 + 16 + lr] = f2bf(p1[r]);
      }
      __asm__ volatile("s_waitcnt lgkmcnt(0)" ::: "memory");
      const short8 pf = *(const short8*)(pl + lr*40 + lq*8);

      #pragma unroll
      for (int nt=0; nt<4; nt++) O[nt] = MFMA16(pf, vf[nt], O[nt]);
    }

    #pragma unroll
    for (int mm=1; mm<16; mm<<=1){
      #pragma unroll
      for (int r=0; r<4; r++) lsum[r] += __shfl_xor(lsum[r], mm);
    }

    if (lr == 0){
      #pragma unroll
      for (int r=0; r<4; r++) lsh[w][lq*4+r] = lsum[r];
    }
    #pragma unroll
    for (int nt=0; nt<4; nt++) *(floatx4*)&Oshf[w][l][nt*4] = O[nt];
    __syncthreads();

    if (w == 0){
      float L[4] = {0.f,0.f,0.f,0.f};
      float Of[4][4];
      #pragma unroll
      for (int nt=0; nt<4; nt++)
        #pragma unroll
        for (int r=0; r<4; r++) Of[nt][r] = 0.f;
      #pragma unroll
      for (int ww=0; ww<4; ww++){
        #pragma unroll
        for (int r=0; r<4; r++) L[r] += lsh[ww][lq*4+r];
        #pragma unroll
        for (int nt=0; nt<4; nt++){
          floatx4 t = *(const floatx4*)&Oshf[ww][l][nt*4];
          #pragma unroll
          for (int r=0; r<4; r++) Of[nt][r] += t[r];
        }
      }
      #pragma unroll
      for (int nt=0; nt<4; nt++){
        #pragma unroll
        for (int r=0; r<4; r++){
          yb[(size_t)(q0 + lq*4 + r)*DIM + head*HD + nt*16 + lr]
              = f2bf(Of[nt][r] / L[r]);
        }
      }
    }
    __syncthreads();
  }
}

// ---------------- output projection (fp32 output, prefetched) ---------------
__global__ __launch_bounds__(256) void proj_kernel(
    const unsigned short* __restrict__ yb,
    const unsigned short* __restrict__ wpb,
    float* __restrict__ out){
  const int w  = threadIdx.x >> 6;
  const int l  = threadIdx.x & 63;
  const int lr = l & 15, lq = l >> 4;
  const int rb = blockIdx.x, cb = blockIdx.y;
  const int row0 = rb*64 + w*16;

  floatx4 acc[4];
  #pragma unroll
  for (int nt=0; nt<4; nt++) acc[nt] = (floatx4){0.f,0.f,0.f,0.f};

  const unsigned short* arow = yb + (size_t)(row0 + lr)*DIM + lq*8;
  const unsigned short* b0   = wpb + (size_t)(cb*64 + lr)*DIM + lq*8;

  short8 a = *(const short8*)(arow);
  short8 b[4];
  #pragma unroll
  for (int nt=0; nt<4; nt++) b[nt] = *(const short8*)(b0 + (size_t)nt*16*DIM);

  for (int k0 = 0; k0 < DIM; k0 += 32){
    const int kn = (k0 + 32 < DIM) ? k0 + 32 : 0;
    short8 an = *(const short8*)(arow + kn);
    short8 bn[4];
    #pragma unroll
    for (int nt=0; nt<4; nt++) bn[nt] = *(const short8*)(b0 + (size_t)nt*16*DIM + kn);
    #pragma unroll
    for (int nt=0; nt<4; nt++) acc[nt] = MFMA16(a, b[nt], acc[nt]);
    a = an;
    #pragma unroll
    for (int nt=0; nt<4; nt++) b[nt] = bn[nt];
  }

  #pragma unroll
  for (int nt=0; nt<4; nt++){
    #pragma unroll
    for (int r=0; r<4; r++){
      out[(size_t)(row0 + lq*4 + r)*DIM + cb*64 + nt*16 + lr] = acc[nt][r];
    }
  }
}

extern "C" void kernel_launch(void* const* d_in, const int* in_sizes, int n_in,
                              void* d_out, int out_size, void* d_ws, size_t ws_size,
                              hipStream_t stream){
  const float* x   = (const float*)d_in[0];
  const float* vi  = (const float*)d_in[1];
  const float* Wq  = (const float*)d_in[2];
  const float* Wk  = (const float*)d_in[3];
  const float* Wv  = (const float*)d_in[4];
  const float* Wp  = (const float*)d_in[5];
  const float* lamb= (const float*)d_in[6];

  const size_t XN = (size_t)T_SEQ*DIM;   // 1572864
  const size_t WN = (size_t)DIM*DIM;     // 589824
  char* ws = (char*)d_ws;
  unsigned short* xb    = (unsigned short*)ws; ws += XN*2;
  unsigned short* wqkvb = (unsigned short*)ws; ws += 3*WN*2;
  unsigned short* wpb   = (unsigned short*)ws; ws += WN*2;
  unsigned short* qb    = (unsigned short*)ws; ws += XN*2;
  unsigned short* kb    = (unsigned short*)ws; ws += XN*2;
  unsigned short* vT    = (unsigned short*)ws; ws += XN*2;
  unsigned short* yb    = xb;  // alias: xb dead after qkv_kernel

  convert_kernel<<<1024, 256, 0, stream>>>(x, Wq, Wk, Wv, Wp, xb, wqkvb, wpb);
  qkv_kernel<<<dim3(32,36), 256, 0, stream>>>(xb, wqkvb, vi, lamb, qb, kb, vT);
  attn_kernel<<<dim3(64,12), 256, 0, stream>>>(qb, kb, vT, yb);
  proj_kernel<<<dim3(32,12), 256, 0, stream>>>(yb, wpb, (float*)d_out);
}

// Round 8
// 188.891 us; speedup vs baseline: 1.3758x; 1.2022x over previous
//
#include <hip/hip_runtime.h>

#define T_SEQ 2048
#define DIM   768
#define NH    12
#define HD    64

typedef __attribute__((ext_vector_type(8))) short short8;
typedef __attribute__((ext_vector_type(4))) float floatx4;
typedef __attribute__((ext_vector_type(4))) unsigned short ushort4v;

#define MFMA16(a,b,c) __builtin_amdgcn_mfma_f32_16x16x32_bf16((a),(b),(c),0,0,0)

static __device__ __forceinline__ unsigned short f2bf(float f){
  union { float f; unsigned u; } v; v.f = f;
  unsigned r = v.u + 0x7fffu + ((v.u >> 16) & 1u);
  return (unsigned short)(r >> 16);
}

// ---------------- fp32 -> bf16 conversion of x, Wq|Wk|Wv, Wp ----------------
__global__ void convert_kernel(const float* __restrict__ x,
                               const float* __restrict__ wq,
                               const float* __restrict__ wk,
                               const float* __restrict__ wv,
                               const float* __restrict__ wp,
                               unsigned short* __restrict__ xb,
                               unsigned short* __restrict__ wqkvb,
                               unsigned short* __restrict__ wpb){
  const int stride = gridDim.x * blockDim.x;
  const int i0 = blockIdx.x * blockDim.x + threadIdx.x;
  const int XN = T_SEQ * DIM;
  const int WN = DIM * DIM;
  for (int i = i0; i < XN; i += stride) xb[i] = f2bf(x[i]);
  for (int i = i0; i < WN; i += stride) {
    wqkvb[i]        = f2bf(wq[i]);
    wqkvb[WN + i]   = f2bf(wk[i]);
    wqkvb[2*WN + i] = f2bf(wv[i]);
    wpb[i]          = f2bf(wp[i]);
  }
}

// ---------------- QKV projection + lerp + rmsnorm + rope --------------------
// One wave per block computes a 64x64 output tile (4x4 MFMA accumulators):
// 16 MFMAs per 8 fragment loads per K-step -> load latency hidden by MFMA
// issue even at ~1 wave/SIMD. grid (32, 36): cb/12 = {q,k,v}, cb%12 = head.
__global__ __launch_bounds__(64) void qkv_kernel(
    const unsigned short* __restrict__ xb,
    const unsigned short* __restrict__ wqkvb,
    const float* __restrict__ vi,
    const float* __restrict__ lambp,
    unsigned short* __restrict__ qb,   // [NH][T][HD]
    unsigned short* __restrict__ kb,   // [NH][T][HD]
    unsigned short* __restrict__ vT){  // [NH][HD][T]
  const int l  = threadIdx.x;
  const int lr = l & 15, lq = l >> 4;
  const int rb = blockIdx.x, cb = blockIdx.y;
  const int mat = cb / NH, head = cb % NH;
  const int row0 = rb*64;

  floatx4 acc[4][4];
  #pragma unroll
  for (int i=0;i<4;i++)
    #pragma unroll
    for (int j=0;j<4;j++) acc[i][j] = (floatx4){0.f,0.f,0.f,0.f};

  const unsigned short* Ab = xb + (size_t)(row0 + lr)*DIM + lq*8;
  const unsigned short* Bb = wqkvb + (size_t)mat*DIM*DIM
                           + (size_t)(head*HD + lr)*DIM + lq*8;

  short8 a[4], b[4];
  #pragma unroll
  for (int rt=0;rt<4;rt++) a[rt] = *(const short8*)(Ab + (size_t)rt*16*DIM);
  #pragma unroll
  for (int ct=0;ct<4;ct++) b[ct] = *(const short8*)(Bb + (size_t)ct*16*DIM);

  for (int k0 = 0; k0 < DIM; k0 += 32){
    const int kn = (k0 + 32 < DIM) ? k0 + 32 : 0;   // wrap tail: unconditional loads
    short8 an[4], bn[4];
    #pragma unroll
    for (int rt=0;rt<4;rt++) an[rt] = *(const short8*)(Ab + (size_t)rt*16*DIM + kn);
    #pragma unroll
    for (int ct=0;ct<4;ct++) bn[ct] = *(const short8*)(Bb + (size_t)ct*16*DIM + kn);
    #pragma unroll
    for (int rt=0;rt<4;rt++)
      #pragma unroll
      for (int ct=0;ct<4;ct++)
        acc[rt][ct] = MFMA16(a[rt], b[ct], acc[rt][ct]);
    #pragma unroll
    for (int rt=0;rt<4;rt++) a[rt] = an[rt];
    #pragma unroll
    for (int ct=0;ct<4;ct++) b[ct] = bn[ct];
  }

  if (mat == 2){
    const float lamb = *lambp;
    #pragma unroll
    for (int rt=0;rt<4;rt++){
      const int tb = row0 + rt*16 + lq*4;
      #pragma unroll
      for (int ct=0;ct<4;ct++){
        const int d = ct*16 + lr;
        ushort4v pk;
        #pragma unroll
        for (int r=0;r<4;r++){
          float vv = (1.0f - lamb)*acc[rt][ct][r]
                   + lamb * vi[(size_t)(tb + r)*DIM + head*HD + d];
          pk[r] = f2bf(vv);
        }
        *(ushort4v*)(vT + (size_t)(head*HD + d)*T_SEQ + tb) = pk;
      }
    }
  } else {
    unsigned short* dst = (mat==0 ? qb : kb) + (size_t)head*T_SEQ*HD;
    #pragma unroll
    for (int rt=0;rt<4;rt++){
      float ss[4];
      #pragma unroll
      for (int r=0;r<4;r++)
        ss[r] = acc[rt][0][r]*acc[rt][0][r] + acc[rt][1][r]*acc[rt][1][r]
              + acc[rt][2][r]*acc[rt][2][r] + acc[rt][3][r]*acc[rt][3][r];
      #pragma unroll
      for (int mm=1; mm<16; mm<<=1){
        #pragma unroll
        for (int r=0;r<4;r++) ss[r] += __shfl_xor(ss[r], mm);
      }
      float scl[4];
      #pragma unroll
      for (int r=0;r<4;r++)
        scl[r] = rsqrtf(ss[r]*(1.0f/64.0f) + 1.1920929e-7f);

      #pragma unroll
      for (int ct=0;ct<2;ct++){
        const int i = ct*16 + lr;               // rope pair index 0..31
        const float inv = __expf(-(float)i * (9.210340371976184f/32.0f));
        #pragma unroll
        for (int r=0;r<4;r++){
          const int t = row0 + rt*16 + lq*4 + r;
          const float f = (float)t * inv;
          const float c = cosf(f), s = sinf(f);
          const float x1 = acc[rt][ct][r]*scl[r], x2 = acc[rt][ct+2][r]*scl[r];
          dst[(size_t)t*HD + i]      = f2bf(x1*c + x2*s);
          dst[(size_t)t*HD + i + 32] = f2bf(x2*c - x1*s);
        }
      }
    }
  }
}

// ---------------- causal flash attention (MFMA, fixed-max softmax) ----------
// Scores bounded: rmsnorm rows have norm 8 => s = q.k/8 in [-8,8]; fixed max.
// grid (64, 12): block b handles q-tiles b and 127-b (balanced).
__global__ __launch_bounds__(256) void attn_kernel(
    const unsigned short* __restrict__ qb,
    const unsigned short* __restrict__ kb,
    const unsigned short* __restrict__ vT,
    unsigned short* __restrict__ yb){   // [T][DIM] token-major
  __shared__ unsigned short plds[2][4][16*40];
  __shared__ float Oshf[4][64][16];
  __shared__ float lsh[4][16];
  const int w  = threadIdx.x >> 6;
  const int l  = threadIdx.x & 63;
  const int lr = l & 15, lq = l >> 4;
  const int head = blockIdx.y;

  const unsigned short* Q = qb + (size_t)head*T_SEQ*HD;
  const unsigned short* K = kb + (size_t)head*T_SEQ*HD;
  const unsigned short* V = vT + (size_t)head*HD*T_SEQ;

  #pragma unroll
  for (int ph = 0; ph < 2; ph++){
    const int qt = ph ? (127 - (int)blockIdx.x) : (int)blockIdx.x;
    const int q0 = qt*16;

    const short8 qf0 = *(const short8*)(Q + (size_t)(q0+lr)*HD + lq*8);
    const short8 qf1 = *(const short8*)(Q + (size_t)(q0+lr)*HD + 32 + lq*8);

    floatx4 O[4];
    #pragma unroll
    for (int nt=0; nt<4; nt++) O[nt] = (floatx4){0.f,0.f,0.f,0.f};
    float lsum[4] = {0.f,0.f,0.f,0.f};

    const int ntile = (q0 + 15)/32 + 1;
    int kt = w;
    short8 kf0, kf1, kf2, kf3;
    if (kt < ntile){
      const unsigned short* kp = K + (size_t)(kt*32 + lr)*HD + lq*8;
      kf0 = *(const short8*)kp;            kf1 = *(const short8*)(kp + 32);
      kf2 = *(const short8*)(kp + 16*HD);  kf3 = *(const short8*)(kp + 16*HD + 32);
    }
    int dbuf = 0;
    for (; kt < ntile; kt += 4, dbuf ^= 1){
      const int kbase = kt*32;
      short8 vf[4];
      #pragma unroll
      for (int nt=0; nt<4; nt++)
        vf[nt] = *(const short8*)(V + (size_t)(nt*16 + lr)*T_SEQ + kbase + lq*8);

      floatx4 S0 = (floatx4){0.f,0.f,0.f,0.f};
      floatx4 S1 = (floatx4){0.f,0.f,0.f,0.f};
      S0 = MFMA16(qf0, kf0, S0);
      S0 = MFMA16(qf1, kf1, S0);
      S1 = MFMA16(qf0, kf2, S1);
      S1 = MFMA16(qf1, kf3, S1);

      const int ktn = kt + 4;
      if (ktn < ntile){
        const unsigned short* kp = K + (size_t)(ktn*32 + lr)*HD + lq*8;
        kf0 = *(const short8*)kp;            kf1 = *(const short8*)(kp + 32);
        kf2 = *(const short8*)(kp + 16*HD);  kf3 = *(const short8*)(kp + 16*HD + 32);
      }

      float p0[4], p1[4];
      const int qr = q0 + lq*4;
      #pragma unroll
      for (int r=0; r<4; r++){
        float e0 = __builtin_amdgcn_exp2f(S0[r]*0.18033688011112043f - 11.541560327111707f);
        float e1 = __builtin_amdgcn_exp2f(S1[r]*0.18033688011112043f - 11.541560327111707f);
        p0[r] = (kbase + lr      > qr + r) ? 0.f : e0;
        p1[r] = (kbase + 16 + lr > qr + r) ? 0.f : e1;
        lsum[r] += p0[r] + p1[r];
      }

      unsigned short* pl = &plds[dbuf][w][0];
      #pragma unroll
      for (int r=0; r<4; r++){
        const int row = lq*4 + r;
        pl[row*40 + lr]      = f2bf(p0[r]);
        pl[row*40 + 16 + lr] = f2bf(p1[r]);
      }
      __asm__ volatile("s_waitcnt lgkmcnt(0)" ::: "memory");
      const short8 pf = *(const short8*)(pl + lr*40 + lq*8);

      #pragma unroll
      for (int nt=0; nt<4; nt++) O[nt] = MFMA16(pf, vf[nt], O[nt]);
    }

    #pragma unroll
    for (int mm=1; mm<16; mm<<=1){
      #pragma unroll
      for (int r=0; r<4; r++) lsum[r] += __shfl_xor(lsum[r], mm);
    }

    if (lr == 0){
      #pragma unroll
      for (int r=0; r<4; r++) lsh[w][lq*4+r] = lsum[r];
    }
    #pragma unroll
    for (int nt=0; nt<4; nt++) *(floatx4*)&Oshf[w][l][nt*4] = O[nt];
    __syncthreads();

    if (w == 0){
      float L[4] = {0.f,0.f,0.f,0.f};
      float Of[4][4];
      #pragma unroll
      for (int nt=0; nt<4; nt++)
        #pragma unroll
        for (int r=0; r<4; r++) Of[nt][r] = 0.f;
      #pragma unroll
      for (int ww=0; ww<4; ww++){
        #pragma unroll
        for (int r=0; r<4; r++) L[r] += lsh[ww][lq*4+r];
        #pragma unroll
        for (int nt=0; nt<4; nt++){
          floatx4 t = *(const floatx4*)&Oshf[ww][l][nt*4];
          #pragma unroll
          for (int r=0; r<4; r++) Of[nt][r] += t[r];
        }
      }
      #pragma unroll
      for (int nt=0; nt<4; nt++){
        #pragma unroll
        for (int r=0; r<4; r++){
          yb[(size_t)(q0 + lq*4 + r)*DIM + head*HD + nt*16 + lr]
              = f2bf(Of[nt][r] / L[r]);
        }
      }
    }
    __syncthreads();
  }
}

// ---------------- output projection (fp32 out, 64x64 per wave) --------------
// grid (32, 12), one wave per block.
__global__ __launch_bounds__(64) void proj_kernel(
    const unsigned short* __restrict__ yb,
    const unsigned short* __restrict__ wpb,
    float* __restrict__ out){
  const int l  = threadIdx.x;
  const int lr = l & 15, lq = l >> 4;
  const int rb = blockIdx.x, cb = blockIdx.y;
  const int row0 = rb*64, col0 = cb*64;

  floatx4 acc[4][4];
  #pragma unroll
  for (int i=0;i<4;i++)
    #pragma unroll
    for (int j=0;j<4;j++) acc[i][j] = (floatx4){0.f,0.f,0.f,0.f};

  const unsigned short* Ab = yb + (size_t)(row0 + lr)*DIM + lq*8;
  const unsigned short* Bb = wpb + (size_t)(col0 + lr)*DIM + lq*8;

  short8 a[4], b[4];
  #pragma unroll
  for (int rt=0;rt<4;rt++) a[rt] = *(const short8*)(Ab + (size_t)rt*16*DIM);
  #pragma unroll
  for (int ct=0;ct<4;ct++) b[ct] = *(const short8*)(Bb + (size_t)ct*16*DIM);

  for (int k0 = 0; k0 < DIM; k0 += 32){
    const int kn = (k0 + 32 < DIM) ? k0 + 32 : 0;
    short8 an[4], bn[4];
    #pragma unroll
    for (int rt=0;rt<4;rt++) an[rt] = *(const short8*)(Ab + (size_t)rt*16*DIM + kn);
    #pragma unroll
    for (int ct=0;ct<4;ct++) bn[ct] = *(const short8*)(Bb + (size_t)ct*16*DIM + kn);
    #pragma unroll
    for (int rt=0;rt<4;rt++)
      #pragma unroll
      for (int ct=0;ct<4;ct++)
        acc[rt][ct] = MFMA16(a[rt], b[ct], acc[rt][ct]);
    #pragma unroll
    for (int rt=0;rt<4;rt++) a[rt] = an[rt];
    #pragma unroll
    for (int ct=0;ct<4;ct++) b[ct] = bn[ct];
  }

  #pragma unroll
  for (int rt=0;rt<4;rt++){
    #pragma unroll
    for (int ct=0;ct<4;ct++){
      const int col = col0 + ct*16 + lr;
      #pragma unroll
      for (int r=0;r<4;r++){
        const int row = row0 + rt*16 + lq*4 + r;
        out[(size_t)row*DIM + col] = acc[rt][ct][r];
      }
    }
  }
}

extern "C" void kernel_launch(void* const* d_in, const int* in_sizes, int n_in,
                              void* d_out, int out_size, void* d_ws, size_t ws_size,
                              hipStream_t stream){
  const float* x   = (const float*)d_in[0];
  const float* vi  = (const float*)d_in[1];
  const float* Wq  = (const float*)d_in[2];
  const float* Wk  = (const float*)d_in[3];
  const float* Wv  = (const float*)d_in[4];
  const float* Wp  = (const float*)d_in[5];
  const float* lamb= (const float*)d_in[6];

  const size_t XN = (size_t)T_SEQ*DIM;   // 1572864
  const size_t WN = (size_t)DIM*DIM;     // 589824
  char* ws = (char*)d_ws;
  unsigned short* xb    = (unsigned short*)ws; ws += XN*2;
  unsigned short* wqkvb = (unsigned short*)ws; ws += 3*WN*2;
  unsigned short* wpb   = (unsigned short*)ws; ws += WN*2;
  unsigned short* qb    = (unsigned short*)ws; ws += XN*2;
  unsigned short* kb    = (unsigned short*)ws; ws += XN*2;
  unsigned short* vT    = (unsigned short*)ws; ws += XN*2;
  unsigned short* yb    = xb;  // alias: xb dead after qkv_kernel

  convert_kernel<<<1024, 256, 0, stream>>>(x, Wq, Wk, Wv, Wp, xb, wqkvb, wpb);
  qkv_kernel<<<dim3(32,36), 64, 0, stream>>>(xb, wqkvb, vi, lamb, qb, kb, vT);
  attn_kernel<<<dim3(64,12), 256, 0, stream>>>(qb, kb, vT, yb);
  proj_kernel<<<dim3(32,12), 64, 0, stream>>>(yb, wpb, (float*)d_out);
}